// Round 14
// baseline (211.891 us; speedup 1.0000x reference)
//
#include <hip/hip_runtime.h>

#define N_TOK 131072
#define K_CODES 512
#define DIM 64
#define MARGIN_S 5e-5f     // s units; screen-vs-np error bound ~2.3e-5 worst
#define LIST_CAP 30000

typedef __attribute__((ext_vector_type(8))) short bfx8;
typedef __attribute__((ext_vector_type(4))) float f32x4;
typedef __attribute__((ext_vector_type(4))) int i32x4;

__device__ __forceinline__ unsigned short f2bf_rn(float f) {
    unsigned u = __float_as_uint(f);
    unsigned r = (u + 0x7FFF + ((u >> 16) & 1)) >> 16;   // RNE (normals only)
    return (unsigned short)r;
}
__device__ __forceinline__ float bf2f(unsigned short h) {
    return __uint_as_float(((unsigned)h) << 16);
}

// numpy pairwise_sum for n=64: 8 strided accumulators + pairwise combine.
__device__ __forceinline__ float np_sumsq64(const float* v) {
    float r[8];
#pragma unroll
    for (int j = 0; j < 8; ++j) r[j] = __fmul_rn(v[j], v[j]);
#pragma unroll
    for (int i = 8; i < 64; i += 8) {
#pragma unroll
        for (int j = 0; j < 8; ++j)
            r[j] = __fadd_rn(r[j], __fmul_rn(v[i + j], v[i + j]));
    }
    return __fadd_rn(__fadd_rn(__fadd_rn(r[0], r[1]), __fadd_rn(r[2], r[3])),
                     __fadd_rn(__fadd_rn(r[4], r[5]), __fadd_rn(r[6], r[7])));
}

// per code: np-exact c2, screening -c2/2 (negated: folds into MFMA acc init),
// and bf16 hi/lo split of the row
__global__ __launch_bounds__(64) void vq_prep(
    const float* __restrict__ cb, float* __restrict__ cnorm,
    float* __restrict__ c2h, unsigned short* __restrict__ cbh,
    unsigned short* __restrict__ cbl)
{
    int k = blockIdx.x * 64 + threadIdx.x;
    if (k >= K_CODES) return;
    float v[DIM];
#pragma unroll
    for (int d = 0; d < DIM; ++d) {
        float f = cb[k * DIM + d];
        v[d] = f;
        unsigned short h = f2bf_rn(f);
        cbh[k * DIM + d] = h;
        cbl[k * DIM + d] = f2bf_rn(__fsub_rn(f, bf2f(h)));
    }
    float c2 = np_sumsq64(v);
    cnorm[k] = c2;
    c2h[k] = __fmul_rn(-0.5f, c2);    // NEGATED half-norm
}

// ---- Phase 1: split-bf16 MFMA screen, 64 tokens/wave, pipelined B reads ----
__global__ __attribute__((amdgpu_flat_work_group_size(256, 256),
                          amdgpu_waves_per_eu(2, 2)))
void vq_screen(
    const float* __restrict__ x, const float* __restrict__ cb,
    const unsigned short* __restrict__ cbh, const unsigned short* __restrict__ cbl,
    const float* __restrict__ c2h, float* __restrict__ out,
    double* __restrict__ loss_acc, int* __restrict__ counter,
    int* __restrict__ list, int cap)
{
    // 128 codes' hi+lo split (32KB) + neg-half-norms (2KB); slot-swizzled
    __shared__ bfx8 lds_h[128 * 8];
    __shared__ bfx8 lds_l[128 * 8];
    __shared__ float lds_c2[K_CODES];
    __shared__ double wsum[4];

    const int tid = threadIdx.x;
    const int wave = (blockIdx.x << 2) + (tid >> 6);
    const int lane = tid & 63;
    const int tokb = wave << 6;           // 64 tokens per wave
    const int lrow = lane & 15;           // A: token row / B: code col
    const int lgrp = lane >> 4;           // k-chunk selector (8 k's each)
    const int lcol = lrow;                // epilogue: dim quad selector

    const float inf = __int_as_float(0x7f800000);

    if (tid < 128) ((float4*)lds_c2)[tid] = ((const float4*)c2h)[tid];

    // ---- load A fragments for 4 token tiles, split to bf16 hi/lo ----
#define SPL(F, J, AH, AL) { unsigned short h_ = f2bf_rn(F); \
    (AH)[J] = (short)h_; (AL)[J] = (short)f2bf_rn(__fsub_rn(F, bf2f(h_))); }
#define LOADX(m) \
    bfx8 ah0_##m, al0_##m, ah1_##m, al1_##m; \
    { const float* xr = x + ((size_t)(tokb + (m) * 16 + lrow) << 6) + (lgrp << 3); \
      float4 f0 = *(const float4*)xr; \
      float4 f1 = *(const float4*)(xr + 4); \
      float4 f2 = *(const float4*)(xr + 32); \
      float4 f3 = *(const float4*)(xr + 36); \
      SPL(f0.x, 0, ah0_##m, al0_##m) SPL(f0.y, 1, ah0_##m, al0_##m) \
      SPL(f0.z, 2, ah0_##m, al0_##m) SPL(f0.w, 3, ah0_##m, al0_##m) \
      SPL(f1.x, 4, ah0_##m, al0_##m) SPL(f1.y, 5, ah0_##m, al0_##m) \
      SPL(f1.z, 6, ah0_##m, al0_##m) SPL(f1.w, 7, ah0_##m, al0_##m) \
      SPL(f2.x, 0, ah1_##m, al1_##m) SPL(f2.y, 1, ah1_##m, al1_##m) \
      SPL(f2.z, 2, ah1_##m, al1_##m) SPL(f2.w, 3, ah1_##m, al1_##m) \
      SPL(f3.x, 4, ah1_##m, al1_##m) SPL(f3.y, 5, ah1_##m, al1_##m) \
      SPL(f3.z, 6, ah1_##m, al1_##m) SPL(f3.w, 7, ah1_##m, al1_##m) }
    LOADX(0) LOADX(1) LOADX(2) LOADX(3)
#undef LOADX
#undef SPL

    f32x4 best0 = {inf, inf, inf, inf}, best1 = best0, best2 = best0, best3 = best0;
    f32x4 sec0 = best0, sec1 = best0, sec2 = best0, sec3 = best0;
    i32x4 idx0 = {0, 0, 0, 0}, idx1 = idx0, idx2 = idx0, idx3 = idx0;

    for (int ph = 0; ph < 4; ++ph) {
        __syncthreads();   // LDS free (entry / previous phase done)
        {
            const bfx8* gh = (const bfx8*)cbh + (ph << 10);
            const bfx8* gl = (const bfx8*)cbl + (ph << 10);
#pragma unroll
            for (int it = 0; it < 4; ++it) {
                int g = (it << 8) + tid;
                int code = g >> 3, slot = g & 7;
                int dst = (code << 3) + (slot ^ (code & 7));
                lds_h[dst] = gh[g];
                lds_l[dst] = gl[g];
            }
        }
        __syncthreads();

        // pipelined inner loop: issue iter i+1's LDS reads before iter i's
        // MFMA cluster so ds_read latency hides under the MFMA issue window.
        int lr_c = lrow;
        int s0_c = lgrp ^ (lr_c & 7);
        bfx8 bh0 = lds_h[(lr_c << 3) + s0_c];
        bfx8 bh1 = lds_h[(lr_c << 3) + (s0_c ^ 4)];
        bfx8 bl0 = lds_l[(lr_c << 3) + s0_c];
        bfx8 bl1 = lds_l[(lr_c << 3) + (s0_c ^ 4)];
        float nc = lds_c2[(ph << 7) + lr_c];    // = -c2/2 (negated in prep)

#pragma unroll
        for (int ctl = 0; ctl < 8; ++ctl) {
            const int code = (ph << 7) + (ctl << 4) + lrow;
            bfx8 nh0 = bh0, nh1 = bh1, nl0 = bl0, nl1 = bl1;
            float ncn = nc;
            if (ctl < 7) {
                int lr_n = ((ctl + 1) << 4) + lrow;
                int s0_n = lgrp ^ (lr_n & 7);
                nh0 = lds_h[(lr_n << 3) + s0_n];
                nh1 = lds_h[(lr_n << 3) + (s0_n ^ 4)];
                nl0 = lds_l[(lr_n << 3) + s0_n];
                nl1 = lds_l[(lr_n << 3) + (s0_n ^ 4)];
                ncn = lds_c2[(ph << 7) + lr_n];
            }

            // 6 MFMAs per tile as TWO independent 3-deep chains (P,Q);
            // P initialized with -c2/2 (all 4 acc elems share col=lrow ->
            // same code -> same nc). al*bl dropped (<=1.7e-5 << margin).
#define MACC(m) \
            f32x4 accP##m = {nc, nc, nc, nc}; \
            f32x4 accQ##m = {0.f, 0.f, 0.f, 0.f}; \
            accP##m = __builtin_amdgcn_mfma_f32_16x16x32_bf16(ah0_##m, bh0, accP##m, 0, 0, 0); \
            accQ##m = __builtin_amdgcn_mfma_f32_16x16x32_bf16(ah1_##m, bh1, accQ##m, 0, 0, 0); \
            accP##m = __builtin_amdgcn_mfma_f32_16x16x32_bf16(al0_##m, bh0, accP##m, 0, 0, 0); \
            accQ##m = __builtin_amdgcn_mfma_f32_16x16x32_bf16(al1_##m, bh1, accQ##m, 0, 0, 0); \
            accP##m = __builtin_amdgcn_mfma_f32_16x16x32_bf16(ah0_##m, bl0, accP##m, 0, 0, 0); \
            accQ##m = __builtin_amdgcn_mfma_f32_16x16x32_bf16(ah1_##m, bl1, accQ##m, 0, 0, 0);
            MACC(0) MACC(1) MACC(2) MACC(3)
#undef MACC

            // s = -(P+Q)  (single v_add with neg modifiers); sec via
            // max/min (no cndmask); idx via cmp+cndmask on s<best_old.
#define UPD1(m, R) { float s = -(accP##m[R] + accQ##m[R]); \
            float mx = fmaxf(s, best##m[R]); \
            sec##m[R] = fminf(sec##m[R], mx); \
            bool p = s < best##m[R]; \
            best##m[R] = fminf(best##m[R], s); \
            idx##m[R] = p ? code : idx##m[R]; }
#define UPDM(m) UPD1(m, 0) UPD1(m, 1) UPD1(m, 2) UPD1(m, 3)
            UPDM(0) UPDM(1) UPDM(2) UPDM(3)
#undef UPDM
#undef UPD1

            bh0 = nh0; bh1 = nh1; bl0 = nl0; bl1 = nl1; nc = ncn;
        }
    }

    // reduce across the 16 lanes of each group (code dim); tie -> lower index
    i32x4 pk0, pk1, pk2, pk3;
#define REDR(m, R) { float b = best##m[R], sc = sec##m[R]; int ix = idx##m[R]; \
    _Pragma("unroll") \
    for (int off = 1; off < 16; off <<= 1) { \
        float ob = __shfl_xor(b, off, 64); \
        float os = __shfl_xor(sc, off, 64); \
        int   oi = __shfl_xor(ix, off, 64); \
        bool take = (ob < b) || (ob == b && oi < ix); \
        float ns = take ? fminf(b, os) : fminf(sc, ob); \
        b = take ? ob : b; ix = take ? oi : ix; sc = ns; } \
    pk##m[R] = ix | (((sc - b) < MARGIN_S) ? (1 << 30) : 0); }
#define REDM(m) REDR(m, 0) REDR(m, 1) REDR(m, 2) REDR(m, 3)
    REDM(0) REDM(1) REDM(2) REDM(3)
#undef REDM
#undef REDR

    // ---- epilogue: per (m,R), lane-group g owns token m*16+g*4+R ----
    double ls = 0.0;
#define EPI1(m, R) { int fi = pk##m[R]; \
    int bidx_t = fi & 0xFFFF; \
    int t = tokb + (m) * 16 + (lgrp << 2) + (R); \
    float4 xv = *((const float4*)(x + ((size_t)t << 6)) + lcol); \
    float4 qv = *((const float4*)(cb + ((size_t)bidx_t << 6)) + lcol); \
    float4 ov; \
    float e0 = __fsub_rn(qv.x, xv.x); ov.x = __fadd_rn(xv.x, e0); \
    float e1 = __fsub_rn(qv.y, xv.y); ov.y = __fadd_rn(xv.y, e1); \
    float e2 = __fsub_rn(qv.z, xv.z); ov.z = __fadd_rn(xv.z, e2); \
    float e3 = __fsub_rn(qv.w, xv.w); ov.w = __fadd_rn(xv.w, e3); \
    *((float4*)(out + ((size_t)t << 6)) + lcol) = ov; \
    if (!(fi >> 30)) \
        ls += (double)e0 * e0 + (double)e1 * e1 + (double)e2 * e2 + (double)e3 * e3; \
    else if (lcol == 0) { int pos = atomicAdd(counter, 1); \
                          if (pos < cap) list[pos] = t; } }
#define EPIM(m) EPI1(m, 0) EPI1(m, 1) EPI1(m, 2) EPI1(m, 3)
    EPIM(0) EPIM(1) EPIM(2) EPIM(3)
#undef EPIM
#undef EPI1

    // block-level loss reduce -> ONE atomic per block
#pragma unroll
    for (int off = 32; off > 0; off >>= 1) ls += __shfl_down(ls, off, 64);
    if (lane == 0) wsum[tid >> 6] = ls;
    __syncthreads();
    if (tid == 0)
        atomicAdd(loss_acc, (wsum[0] + wsum[1]) + (wsum[2] + wsum[3]));
}

// ---- Phase 2: np-exact full re-scan of flagged tokens + fused finalize -----
#define RERANK_BLOCKS 256
__global__ __launch_bounds__(256) void vq_rerank(
    const float* __restrict__ x, const float* __restrict__ cb,
    const float* __restrict__ cnorm, float* __restrict__ out,
    double* __restrict__ loss_acc, const int* __restrict__ counter,
    const int* __restrict__ list, int cap,
    int* __restrict__ done, float* __restrict__ out_loss)
{
    int cnt = *counter; if (cnt > cap) cnt = cap;
    const int lane = threadIdx.x & 63;
    const int wid = (blockIdx.x << 2) + (threadIdx.x >> 6);
    const int nw = RERANK_BLOCKS << 2;
    double ls = 0.0;

    for (int i = wid; i < cnt; i += nw) {
        const int t = list[i];
        float xr[DIM];
        {
            const float4* xv = (const float4*)(x + ((size_t)t << 6));
#pragma unroll
            for (int q = 0; q < 16; ++q) {
                float4 v = xv[q];
                xr[4 * q + 0] = v.x; xr[4 * q + 1] = v.y;
                xr[4 * q + 2] = v.z; xr[4 * q + 3] = v.w;
            }
        }
        const float x2 = np_sumsq64(xr);
        float best = __int_as_float(0x7f800000);
        int bi = 0;
#pragma unroll 2
        for (int j = 0; j < 8; ++j) {
            const int k = (j << 6) + lane;       // per-lane ascending k
            const float4* c = (const float4*)(cb + ((size_t)k << 6));
            float a = 0.f;
#pragma unroll
            for (int q = 0; q < 16; ++q) {       // float4 loads, chain d-asc
                float4 f = c[q];
                a = __fmaf_rn(xr[4 * q + 0], f.x, a);
                a = __fmaf_rn(xr[4 * q + 1], f.y, a);
                a = __fmaf_rn(xr[4 * q + 2], f.z, a);
                a = __fmaf_rn(xr[4 * q + 3], f.w, a);
            }
            float d2 = __fadd_rn(__fsub_rn(x2, __fmul_rn(2.0f, a)), cnorm[k]);
            bool p = d2 < best;
            best = p ? d2 : best; bi = p ? k : bi;
        }
#pragma unroll
        for (int off = 1; off < 64; off <<= 1) {
            float ob = __shfl_xor(best, off, 64);
            int   oi = __shfl_xor(bi, off, 64);
            bool take = (ob < best) || (ob == best && oi < bi);
            best = take ? ob : best; bi = take ? oi : bi;
        }
        float xv = x[((size_t)t << 6) + lane];
        float q  = cb[((size_t)bi << 6) + lane];
        float e = __fsub_rn(q, xv);
        out[((size_t)t << 6) + lane] = __fadd_rn(xv, e);
        ls += (double)e * (double)e;
    }
#pragma unroll
    for (int off = 32; off > 0; off >>= 1) ls += __shfl_down(ls, off, 64);
    __shared__ double wsum[4];
    if (lane == 0) wsum[threadIdx.x >> 6] = ls;
    __syncthreads();
    if (threadIdx.x == 0) {
        double tot = (wsum[0] + wsum[1]) + (wsum[2] + wsum[3]);
        if (tot != 0.0) atomicAdd(loss_acc, tot);
        __threadfence();
        int prev = atomicAdd(done, 1);
        if (prev == RERANK_BLOCKS - 1) {       // last block: finalize loss
            __threadfence();
            double total = atomicAdd(loss_acc, 0.0);   // coherent read
            double mean = total / (double)((size_t)N_TOK * DIM);
            *out_loss = (float)(1.25 * mean);
        }
    }
}

extern "C" void kernel_launch(void* const* d_in, const int* in_sizes, int n_in,
                              void* d_out, int out_size, void* d_ws, size_t ws_size,
                              hipStream_t stream) {
    const float* x  = (const float*)d_in[0];
    const float* cb = (const float*)d_in[1];
    float* out = (float*)d_out;
    float* out_loss = out + (size_t)N_TOK * DIM;

    char* ws = (char*)d_ws;
    double* loss_acc = (double*)ws;                       // [0,8)
    int* counter = (int*)(ws + 8);                        // [8,12)
    int* done = (int*)(ws + 12);                          // [12,16)
    float* cnorm = (float*)(ws + 64);                     // 2KB
    float* c2h = (float*)(ws + 2112);                     // 2KB (negated)
    unsigned short* cbh = (unsigned short*)(ws + 4608);   // 64KB
    unsigned short* cbl = (unsigned short*)(ws + 70144);  // 64KB
    int* list = (int*)(ws + 135680);                      // 120KB

    hipMemsetAsync(d_ws, 0, 32, stream);
    vq_prep<<<8, 64, 0, stream>>>(cb, cnorm, c2h, cbh, cbl);
    vq_screen<<<N_TOK / 256, 256, 0, stream>>>(x, cb, cbh, cbl, c2h, out,
                                               loss_acc, counter, list, LIST_CAP);
    vq_rerank<<<RERANK_BLOCKS, 256, 0, stream>>>(x, cb, cnorm, out, loss_acc,
                                                 counter, list, LIST_CAP,
                                                 done, out_loss);
}

// Round 15
// 83.653 us; speedup vs baseline: 2.5330x; 2.5330x over previous
//
#include <hip/hip_runtime.h>

#define N_TOK 131072
#define K_CODES 512
#define DIM 64
#define MARGIN_S 5e-5f     // s units; screen-vs-np error bound ~2.3e-5 worst
#define LIST_CAP 30000

typedef __attribute__((ext_vector_type(8))) short bfx8;
typedef __attribute__((ext_vector_type(4))) float f32x4;
typedef __attribute__((ext_vector_type(4))) int i32x4;

__device__ __forceinline__ unsigned short f2bf_rn(float f) {
    unsigned u = __float_as_uint(f);
    unsigned r = (u + 0x7FFF + ((u >> 16) & 1)) >> 16;   // RNE (normals only)
    return (unsigned short)r;
}
__device__ __forceinline__ float bf2f(unsigned short h) {
    return __uint_as_float(((unsigned)h) << 16);
}

// numpy pairwise_sum for n=64: 8 strided accumulators + pairwise combine.
__device__ __forceinline__ float np_sumsq64(const float* v) {
    float r[8];
#pragma unroll
    for (int j = 0; j < 8; ++j) r[j] = __fmul_rn(v[j], v[j]);
#pragma unroll
    for (int i = 8; i < 64; i += 8) {
#pragma unroll
        for (int j = 0; j < 8; ++j)
            r[j] = __fadd_rn(r[j], __fmul_rn(v[i + j], v[i + j]));
    }
    return __fadd_rn(__fadd_rn(__fadd_rn(r[0], r[1]), __fadd_rn(r[2], r[3])),
                     __fadd_rn(__fadd_rn(r[4], r[5]), __fadd_rn(r[6], r[7])));
}

// per code: np-exact c2, screening c2/2, and bf16 hi/lo split of the row
__global__ __launch_bounds__(64) void vq_prep(
    const float* __restrict__ cb, float* __restrict__ cnorm,
    float* __restrict__ c2h, unsigned short* __restrict__ cbh,
    unsigned short* __restrict__ cbl)
{
    int k = blockIdx.x * 64 + threadIdx.x;
    if (k >= K_CODES) return;
    float v[DIM];
#pragma unroll
    for (int d = 0; d < DIM; ++d) {
        float f = cb[k * DIM + d];
        v[d] = f;
        unsigned short h = f2bf_rn(f);
        cbh[k * DIM + d] = h;
        cbl[k * DIM + d] = f2bf_rn(__fsub_rn(f, bf2f(h)));
    }
    float c2 = np_sumsq64(v);
    cnorm[k] = c2;
    c2h[k] = __fmul_rn(0.5f, c2);
}

// ---- Phase 1: split-bf16 MFMA screen, 64 tokens/wave, pipelined B reads ----
// (R11 structure verbatim: measured 57.7us, VGPR 128, no spill)
__global__ __attribute__((amdgpu_flat_work_group_size(256, 256),
                          amdgpu_waves_per_eu(2, 2)))
void vq_screen(
    const float* __restrict__ x, const float* __restrict__ cb,
    const unsigned short* __restrict__ cbh, const unsigned short* __restrict__ cbl,
    const float* __restrict__ c2h, float* __restrict__ out,
    double* __restrict__ loss_acc, int* __restrict__ counter,
    int* __restrict__ list, int cap)
{
    // 128 codes' hi+lo split (32KB) + c2h (2KB); slot-swizzled (x^(row&7))
    __shared__ bfx8 lds_h[128 * 8];
    __shared__ bfx8 lds_l[128 * 8];
    __shared__ float lds_c2[K_CODES];
    __shared__ double wsum[4];

    const int tid = threadIdx.x;
    const int wave = (blockIdx.x << 2) + (tid >> 6);
    const int lane = tid & 63;
    const int tokb = wave << 6;           // 64 tokens per wave
    const int lrow = lane & 15;           // A: token row / B: code col
    const int lgrp = lane >> 4;           // k-chunk selector (8 k's each)
    const int lcol = lrow;                // epilogue: dim quad selector

    const float inf = __int_as_float(0x7f800000);

    if (tid < 128) ((float4*)lds_c2)[tid] = ((const float4*)c2h)[tid];

    // ---- load A fragments for 4 token tiles, split to bf16 hi/lo ----
#define SPL(F, J, AH, AL) { unsigned short h_ = f2bf_rn(F); \
    (AH)[J] = (short)h_; (AL)[J] = (short)f2bf_rn(__fsub_rn(F, bf2f(h_))); }
#define LOADX(m) \
    bfx8 ah0_##m, al0_##m, ah1_##m, al1_##m; \
    { const float* xr = x + ((size_t)(tokb + (m) * 16 + lrow) << 6) + (lgrp << 3); \
      float4 f0 = *(const float4*)xr; \
      float4 f1 = *(const float4*)(xr + 4); \
      float4 f2 = *(const float4*)(xr + 32); \
      float4 f3 = *(const float4*)(xr + 36); \
      SPL(f0.x, 0, ah0_##m, al0_##m) SPL(f0.y, 1, ah0_##m, al0_##m) \
      SPL(f0.z, 2, ah0_##m, al0_##m) SPL(f0.w, 3, ah0_##m, al0_##m) \
      SPL(f1.x, 4, ah0_##m, al0_##m) SPL(f1.y, 5, ah0_##m, al0_##m) \
      SPL(f1.z, 6, ah0_##m, al0_##m) SPL(f1.w, 7, ah0_##m, al0_##m) \
      SPL(f2.x, 0, ah1_##m, al1_##m) SPL(f2.y, 1, ah1_##m, al1_##m) \
      SPL(f2.z, 2, ah1_##m, al1_##m) SPL(f2.w, 3, ah1_##m, al1_##m) \
      SPL(f3.x, 4, ah1_##m, al1_##m) SPL(f3.y, 5, ah1_##m, al1_##m) \
      SPL(f3.z, 6, ah1_##m, al1_##m) SPL(f3.w, 7, ah1_##m, al1_##m) }
    LOADX(0) LOADX(1) LOADX(2) LOADX(3)
#undef LOADX
#undef SPL

    f32x4 best0 = {inf, inf, inf, inf}, best1 = best0, best2 = best0, best3 = best0;
    f32x4 sec0 = best0, sec1 = best0, sec2 = best0, sec3 = best0;
    i32x4 idx0 = {0, 0, 0, 0}, idx1 = idx0, idx2 = idx0, idx3 = idx0;

    for (int ph = 0; ph < 4; ++ph) {
        __syncthreads();   // LDS free (entry / previous phase done)
        {
            const bfx8* gh = (const bfx8*)cbh + (ph << 10);
            const bfx8* gl = (const bfx8*)cbl + (ph << 10);
#pragma unroll
            for (int it = 0; it < 4; ++it) {
                int g = (it << 8) + tid;
                int code = g >> 3, slot = g & 7;
                int dst = (code << 3) + (slot ^ (code & 7));
                lds_h[dst] = gh[g];
                lds_l[dst] = gl[g];
            }
        }
        __syncthreads();

        // pipelined inner loop: issue iter i+1's LDS reads before iter i's
        // MFMA cluster so ds_read latency hides under the MFMA issue window.
        int lr_c = lrow;
        int s0_c = lgrp ^ (lr_c & 7);
        bfx8 bh0 = lds_h[(lr_c << 3) + s0_c];
        bfx8 bh1 = lds_h[(lr_c << 3) + (s0_c ^ 4)];
        bfx8 bl0 = lds_l[(lr_c << 3) + s0_c];
        bfx8 bl1 = lds_l[(lr_c << 3) + (s0_c ^ 4)];
        float cn = lds_c2[(ph << 7) + lr_c];

#pragma unroll
        for (int ctl = 0; ctl < 8; ++ctl) {
            const int code = (ph << 7) + (ctl << 4) + lrow;
            bfx8 nh0 = bh0, nh1 = bh1, nl0 = bl0, nl1 = bl1;
            float cnn = cn;
            if (ctl < 7) {
                int lr_n = ((ctl + 1) << 4) + lrow;
                int s0_n = lgrp ^ (lr_n & 7);
                nh0 = lds_h[(lr_n << 3) + s0_n];
                nh1 = lds_h[(lr_n << 3) + (s0_n ^ 4)];
                nl0 = lds_l[(lr_n << 3) + s0_n];
                nl1 = lds_l[(lr_n << 3) + (s0_n ^ 4)];
                cnn = lds_c2[(ph << 7) + lr_n];
            }

            // 6 MFMAs per tile as TWO independent 3-deep chains (P,Q);
            // al*bl dropped (|sum| <= ~1.7e-5 worst case << margin).
#define MACC(m) \
            f32x4 accP##m = {0.f, 0.f, 0.f, 0.f}; \
            f32x4 accQ##m = {0.f, 0.f, 0.f, 0.f}; \
            accP##m = __builtin_amdgcn_mfma_f32_16x16x32_bf16(ah0_##m, bh0, accP##m, 0, 0, 0); \
            accQ##m = __builtin_amdgcn_mfma_f32_16x16x32_bf16(ah1_##m, bh1, accQ##m, 0, 0, 0); \
            accP##m = __builtin_amdgcn_mfma_f32_16x16x32_bf16(al0_##m, bh0, accP##m, 0, 0, 0); \
            accQ##m = __builtin_amdgcn_mfma_f32_16x16x32_bf16(al1_##m, bh1, accQ##m, 0, 0, 0); \
            accP##m = __builtin_amdgcn_mfma_f32_16x16x32_bf16(ah0_##m, bl0, accP##m, 0, 0, 0); \
            accQ##m = __builtin_amdgcn_mfma_f32_16x16x32_bf16(ah1_##m, bl1, accQ##m, 0, 0, 0);
            MACC(0) MACC(1) MACC(2) MACC(3)
#undef MACC

#define UPD1(m, R) { float s = cn - (accP##m[R] + accQ##m[R]); \
            bool p = s < best##m[R]; \
            sec##m[R] = p ? best##m[R] : fminf(sec##m[R], s); \
            best##m[R] = p ? s : best##m[R]; \
            idx##m[R] = p ? code : idx##m[R]; }
#define UPDM(m) UPD1(m, 0) UPD1(m, 1) UPD1(m, 2) UPD1(m, 3)
            UPDM(0) UPDM(1) UPDM(2) UPDM(3)
#undef UPDM
#undef UPD1

            bh0 = nh0; bh1 = nh1; bl0 = nl0; bl1 = nl1; cn = cnn;
        }
    }

    // reduce across the 16 lanes of each group (code dim); tie -> lower index
    i32x4 pk0, pk1, pk2, pk3;
#define REDR(m, R) { float b = best##m[R], sc = sec##m[R]; int ix = idx##m[R]; \
    _Pragma("unroll") \
    for (int off = 1; off < 16; off <<= 1) { \
        float ob = __shfl_xor(b, off, 64); \
        float os = __shfl_xor(sc, off, 64); \
        int   oi = __shfl_xor(ix, off, 64); \
        bool take = (ob < b) || (ob == b && oi < ix); \
        float ns = take ? fminf(b, os) : fminf(sc, ob); \
        b = take ? ob : b; ix = take ? oi : ix; sc = ns; } \
    pk##m[R] = ix | (((sc - b) < MARGIN_S) ? (1 << 30) : 0); }
#define REDM(m) REDR(m, 0) REDR(m, 1) REDR(m, 2) REDR(m, 3)
    REDM(0) REDM(1) REDM(2) REDM(3)
#undef REDM
#undef REDR

    // ---- epilogue: per (m,R), lane-group g owns token m*16+g*4+R ----
    double ls = 0.0;
#define EPI1(m, R) { int fi = pk##m[R]; \
    int bidx_t = fi & 0xFFFF; \
    int t = tokb + (m) * 16 + (lgrp << 2) + (R); \
    float4 xv = *((const float4*)(x + ((size_t)t << 6)) + lcol); \
    float4 qv = *((const float4*)(cb + ((size_t)bidx_t << 6)) + lcol); \
    float4 ov; \
    float e0 = __fsub_rn(qv.x, xv.x); ov.x = __fadd_rn(xv.x, e0); \
    float e1 = __fsub_rn(qv.y, xv.y); ov.y = __fadd_rn(xv.y, e1); \
    float e2 = __fsub_rn(qv.z, xv.z); ov.z = __fadd_rn(xv.z, e2); \
    float e3 = __fsub_rn(qv.w, xv.w); ov.w = __fadd_rn(xv.w, e3); \
    *((float4*)(out + ((size_t)t << 6)) + lcol) = ov; \
    if (!(fi >> 30)) \
        ls += (double)e0 * e0 + (double)e1 * e1 + (double)e2 * e2 + (double)e3 * e3; \
    else if (lcol == 0) { int pos = atomicAdd(counter, 1); \
                          if (pos < cap) list[pos] = t; } }
#define EPIM(m) EPI1(m, 0) EPI1(m, 1) EPI1(m, 2) EPI1(m, 3)
    EPIM(0) EPIM(1) EPIM(2) EPIM(3)
#undef EPIM
#undef EPI1

    // block-level loss reduce -> ONE atomic per block
#pragma unroll
    for (int off = 32; off > 0; off >>= 1) ls += __shfl_down(ls, off, 64);
    if (lane == 0) wsum[tid >> 6] = ls;
    __syncthreads();
    if (tid == 0)
        atomicAdd(loss_acc, (wsum[0] + wsum[1]) + (wsum[2] + wsum[3]));
}

// ---- Phase 2: np-exact full re-scan of flagged tokens + fused finalize -----
#define RERANK_BLOCKS 256
__global__ __launch_bounds__(256) void vq_rerank(
    const float* __restrict__ x, const float* __restrict__ cb,
    const float* __restrict__ cnorm, float* __restrict__ out,
    double* __restrict__ loss_acc, const int* __restrict__ counter,
    const int* __restrict__ list, int cap,
    int* __restrict__ done, float* __restrict__ out_loss)
{
    int cnt = *counter; if (cnt > cap) cnt = cap;
    const int lane = threadIdx.x & 63;
    const int wid = (blockIdx.x << 2) + (threadIdx.x >> 6);
    const int nw = RERANK_BLOCKS << 2;
    double ls = 0.0;

    for (int i = wid; i < cnt; i += nw) {
        const int t = list[i];
        float xr[DIM];
        {
            const float4* xv = (const float4*)(x + ((size_t)t << 6));
#pragma unroll
            for (int q = 0; q < 16; ++q) {
                float4 v = xv[q];
                xr[4 * q + 0] = v.x; xr[4 * q + 1] = v.y;
                xr[4 * q + 2] = v.z; xr[4 * q + 3] = v.w;
            }
        }
        const float x2 = np_sumsq64(xr);
        float best = __int_as_float(0x7f800000);
        int bi = 0;
#pragma unroll 2
        for (int j = 0; j < 8; ++j) {
            const int k = (j << 6) + lane;       // per-lane ascending k
            const float4* c = (const float4*)(cb + ((size_t)k << 6));
            float a = 0.f;
#pragma unroll
            for (int q = 0; q < 16; ++q) {       // float4 loads, chain d-asc
                float4 f = c[q];
                a = __fmaf_rn(xr[4 * q + 0], f.x, a);
                a = __fmaf_rn(xr[4 * q + 1], f.y, a);
                a = __fmaf_rn(xr[4 * q + 2], f.z, a);
                a = __fmaf_rn(xr[4 * q + 3], f.w, a);
            }
            float d2 = __fadd_rn(__fsub_rn(x2, __fmul_rn(2.0f, a)), cnorm[k]);
            bool p = d2 < best;
            best = p ? d2 : best; bi = p ? k : bi;
        }
#pragma unroll
        for (int off = 1; off < 64; off <<= 1) {
            float ob = __shfl_xor(best, off, 64);
            int   oi = __shfl_xor(bi, off, 64);
            bool take = (ob < best) || (ob == best && oi < bi);
            best = take ? ob : best; bi = take ? oi : bi;
        }
        float xv = x[((size_t)t << 6) + lane];
        float q  = cb[((size_t)bi << 6) + lane];
        float e = __fsub_rn(q, xv);
        out[((size_t)t << 6) + lane] = __fadd_rn(xv, e);
        ls += (double)e * (double)e;
    }
#pragma unroll
    for (int off = 32; off > 0; off >>= 1) ls += __shfl_down(ls, off, 64);
    __shared__ double wsum[4];
    if (lane == 0) wsum[threadIdx.x >> 6] = ls;
    __syncthreads();
    if (threadIdx.x == 0) {
        double tot = (wsum[0] + wsum[1]) + (wsum[2] + wsum[3]);
        if (tot != 0.0) atomicAdd(loss_acc, tot);
        __threadfence();
        int prev = atomicAdd(done, 1);
        if (prev == RERANK_BLOCKS - 1) {       // last block: finalize loss
            __threadfence();
            double total = atomicAdd(loss_acc, 0.0);   // coherent read
            double mean = total / (double)((size_t)N_TOK * DIM);
            *out_loss = (float)(1.25 * mean);
        }
    }
}

extern "C" void kernel_launch(void* const* d_in, const int* in_sizes, int n_in,
                              void* d_out, int out_size, void* d_ws, size_t ws_size,
                              hipStream_t stream) {
    const float* x  = (const float*)d_in[0];
    const float* cb = (const float*)d_in[1];
    float* out = (float*)d_out;
    float* out_loss = out + (size_t)N_TOK * DIM;

    char* ws = (char*)d_ws;
    double* loss_acc = (double*)ws;                       // [0,8)
    int* counter = (int*)(ws + 8);                        // [8,12)
    int* done = (int*)(ws + 12);                          // [12,16)
    float* cnorm = (float*)(ws + 64);                     // 2KB
    float* c2h = (float*)(ws + 2112);                     // 2KB
    unsigned short* cbh = (unsigned short*)(ws + 4608);   // 64KB
    unsigned short* cbl = (unsigned short*)(ws + 70144);  // 64KB
    int* list = (int*)(ws + 135680);                      // 120KB

    hipMemsetAsync(d_ws, 0, 32, stream);
    vq_prep<<<8, 64, 0, stream>>>(cb, cnorm, c2h, cbh, cbl);
    vq_screen<<<N_TOK / 256, 256, 0, stream>>>(x, cb, cbh, cbl, c2h, out,
                                               loss_acc, counter, list, LIST_CAP);
    vq_rerank<<<RERANK_BLOCKS, 256, 0, stream>>>(x, cb, cnorm, out, loss_acc,
                                                 counter, list, LIST_CAP,
                                                 done, out_loss);
}